// Round 1
// baseline (255.095 us; speedup 1.0000x reference)
//
#include <hip/hip_runtime.h>
#include <hip/hip_cooperative_groups.h>

namespace cg = cooperative_groups;

#define NN 100000
#define BB 64
#define EE 1600000
#define FD 128
#define SLOTC 64                 // per-graph kept-row capacity (actual: ~1)
#define KSLOTS (BB * SLOTC)
#define EMAXE (1 << 20)
#define NWORDS (NN / 32)         // 3125 exactly (100000 % 32 == 0)
#define STR 391                  // ceil(NN/256)
#define GRID_F 256               // fused cooperative grid (1 block/CU)

struct KArgs {
    const float2* x; const int4* src4; const int* ei; const int* bidx; const float* tw;
    const float *W1,*b1,*g1,*be1,*rm1,*rv1;
    const float *W2,*b2,*g2,*be2,*rm2,*rv2;
    const float *W3,*b3,*g3,*be3,*rm3,*rv3;
    const float *linW,*linb;
    unsigned* kfbits; int* nslot; int* knt; float* degs; float2* h0s;
    int* kedge; int* kecnt; float* hY; float* out;
};

struct LdsScore { int ired[256]; float red[256]; int klist[SLOTC]; int lcnt; float shv; };
struct LdsTail  { float tileA[SLOTC*FD]; float tileB[SLOTC*FD]; float2 psl[SLOTC];
                  float poolv[FD]; float rowt[FD]; };

// parallel lower_bound over sorted bidx: first idx in [0,NN] with bidx[idx]>=v.
// All 256 threads participate (contains __syncthreads).
__device__ __forceinline__ int plower(const int* __restrict__ bidx, int v,
                                      int tid, int* ired) {
    int p = tid * STR;                       // max 99705 < NN
    int val = bidx[p];
    ired[tid] = (val < v) ? tid : -1;
    __syncthreads();
    for (int s = 128; s > 0; s >>= 1) { if (tid < s) ired[tid] = max(ired[tid], ired[tid + s]); __syncthreads(); }
    int t0 = ired[0];
    __syncthreads();
    if (t0 < 0) return 0;
    int lo = t0 * STR;                       // bidx[lo] < v
    int hi = lo + STR; if (hi > NN) hi = NN; // answer in (lo, hi]
    int ans = hi;
    for (int q = lo + 1 + tid; q < hi; q += 256) {
        if (bidx[q] >= v) { ans = q; break; }// per-thread probes ascending
    }
    ired[tid] = ans;
    __syncthreads();
    for (int s = 128; s > 0; s >>= 1) { if (tid < s) ired[tid] = min(ired[tid], ired[tid + s]); __syncthreads(); }
    int r = ired[0];
    __syncthreads();
    return r;
}

// Phase 1 (== old K1): per-graph softmax score, keep test, slot alloc, h0/deg init.
__device__ void phase_score(const KArgs& a, int b, int tid, LdsScore& L) {
    if (tid == 0) { L.lcnt = 0; if (b == 0) { a.kecnt[0] = 0; a.kecnt[1] = 0; } }
    int s0 = plower(a.bidx, b, tid, L.ired);
    int e0 = plower(a.bidx, b + 1, tid, L.ired);
    int Ln = e0 - s0;
    float w0 = a.tw[0], w1 = a.tw[1];

    // clear my slice of keep-bits. Interior words: plain store. Boundary words:
    // atomicAnd own-bits mask (disjoint vs neighbors -> commutes).
    if (Ln > 0) {
        int wlo = s0 >> 5, whi = (e0 - 1) >> 5;
        for (int w = wlo + tid; w <= whi; w += 256) {
            unsigned mask = 0xFFFFFFFFu;
            if (w == wlo) mask &= (0xFFFFFFFFu << (s0 & 31));
            if (w == whi) mask &= (0xFFFFFFFFu >> (31 - ((e0 - 1) & 31)));
            if (mask == 0xFFFFFFFFu) a.kfbits[w] = 0u;
            else atomicAnd(&a.kfbits[w], ~mask);
        }
    }

    // pass 1: max logit
    float mx = -3.4028235e38f;
    for (int j = tid; j < Ln; j += 256) {
        float2 v = a.x[s0 + j];
        mx = fmaxf(mx, v.x * w0 + v.y * w1);
    }
    L.red[tid] = mx; __syncthreads();
    for (int s = 128; s > 0; s >>= 1) { if (tid < s) L.red[tid] = fmaxf(L.red[tid], L.red[tid + s]); __syncthreads(); }
    if (tid == 0) L.shv = L.red[0];
    __syncthreads();
    float m = L.shv;

    // pass 2: S = sum exp(l - m)
    float sm = 0.f;
    for (int j = tid; j < Ln; j += 256) {
        float2 v = a.x[s0 + j];
        sm += expf(v.x * w0 + v.y * w1 - m);
    }
    L.red[tid] = sm; __syncthreads();
    for (int s = 128; s > 0; s >>= 1) { if (tid < s) L.red[tid] += L.red[tid + s]; __syncthreads(); }
    if (tid == 0) L.shv = L.red[0];
    __syncthreads();
    float S = L.shv;
    float thr = fminf(1.0f / S - 1e-7f, 0.1f);

    // pass 3: keep test + slot claim
    for (int j = tid; j < Ln; j += 256) {
        float2 v = a.x[s0 + j];
        float sc = expf(v.x * w0 + v.y * w1 - m) / S;
        if (sc > thr) {
            int l = atomicAdd(&L.lcnt, 1);
            if (l < SLOTC) L.klist[l] = j;
        }
    }
    __syncthreads();
    int nk = L.lcnt; if (nk > SLOTC) nk = SLOTC;
    if (tid == 0) a.knt[b] = nk;
    for (int l = tid; l < nk; l += 256) {
        int i = s0 + L.klist[l];
        float2 v = a.x[i];
        float sc = expf(v.x * w0 + v.y * w1 - m) / S;
        int slot = b * SLOTC + l;
        atomicOr(&a.kfbits[i >> 5], 1u << (i & 31));
        a.nslot[i] = slot;
        a.degs[slot] = 1.0f;                 // self-loop
        a.h0s[slot] = make_float2(v.x * sc, v.y * sc);
    }
}

// Phase 2 (== old K2): edge scan, 4 edges per t; dst probed only on src-kept.
__device__ void phase_edges(const KArgs& a, int t0, int stride) {
    const int M = EE / 4;
    for (int t = t0; t < M; t += stride) {
        int4 s4 = a.src4[t];
        int ss[4] = {s4.x, s4.y, s4.z, s4.w};
        #pragma unroll
        for (int q = 0; q < 4; q++) {
            int s = ss[q];
            if ((a.kfbits[s >> 5] >> (s & 31)) & 1u) {
                int d = a.ei[EE + t * 4 + q];
                if ((a.kfbits[d >> 5] >> (d & 31)) & 1u) {
                    int ds = a.nslot[d], sl = a.nslot[s];
                    atomicAdd(&a.degs[ds], 1.0f);
                    int idx = atomicAdd(&a.kecnt[0], 1);
                    if (idx < EMAXE) { a.kedge[2 * idx] = sl; a.kedge[2 * idx + 1] = ds; }
                    if ((sl >> 6) != (ds >> 6)) atomicAdd(&a.kecnt[1], 1);
                }
            }
        }
    }
}

// Tail common part: layer-1 agg + h1 + mm2 -> T.tileB (== old K3 head).
__device__ void tail_common(const KArgs& a, int b, int tid, LdsTail& T, int ke, int nk) {
    for (int j = tid; j < SLOTC; j += 256) T.psl[j] = make_float2(0.f, 0.f);
    __syncthreads();
    for (int t = tid; t < ke; t += 256) {
        int d = a.kedge[2 * t + 1];
        if ((d >> 6) == b) {
            int s = a.kedge[2 * t];
            float nm = rsqrtf(a.degs[s]) * rsqrtf(a.degs[d]);
            float2 h = a.h0s[s];
            atomicAdd(&T.psl[d & 63].x, nm * h.x);
            atomicAdd(&T.psl[d & 63].y, nm * h.y);
        }
    }
    __syncthreads();
    for (int j = tid; j < nk * FD; j += 256) {
        int ld = j >> 7, f = j & 127, slot = b * SLOTC + ld;
        float di = rsqrtf(a.degs[slot]), d2 = di * di;
        float2 h = a.h0s[slot];
        float a0 = T.psl[ld].x + d2 * h.x;
        float a1 = T.psl[ld].y + d2 * h.y;
        float v = a0 * a.W1[f] + a1 * a.W1[FD + f] + a.b1[f];
        v = fmaxf(v, 0.f);
        v = (v - a.rm1[f]) * rsqrtf(a.rv1[f] + 1e-5f) * a.g1[f] + a.be1[f];
        T.tileA[j] = v;
    }
    __syncthreads();
    for (int j = tid; j < nk * FD; j += 256) {
        int ld = j >> 7, f = j & 127;
        const float* xr = T.tileA + ld * FD;
        float acc = 0.f;
        #pragma unroll 8
        for (int k = 0; k < FD; k++) acc += xr[k] * a.W2[k * FD + f];
        T.tileB[j] = acc;
    }
    __syncthreads();
}

__device__ void tail_write_hY(const KArgs& a, int b, int tid, LdsTail& T, int nk) {
    for (int j = tid; j < nk * FD; j += 256) {
        int ld = j >> 7, f = j & 127;
        a.hY[(b * SLOTC + ld) * FD + f] = T.tileB[j];
    }
}

// pool + linear + log_softmax (expects h3 in T.tileA, preceded by a sync).
__device__ void tail_out(const KArgs& a, int b, int tid, LdsTail& T, int nk) {
    for (int f = tid; f < FD; f += 256) {
        float mx = -3.4028235e38f;
        for (int ld = 0; ld < nk; ld++) mx = fmaxf(mx, T.tileA[ld * FD + f]);
        T.poolv[f] = mx;
    }
    __syncthreads();
    if (tid == 0) {
        float z0 = a.linb[0], z1 = a.linb[1], z2 = a.linb[2];
        for (int f = 0; f < FD; f++) {
            float pv = T.poolv[f];
            z0 += pv * a.linW[f * 3 + 0];
            z1 += pv * a.linW[f * 3 + 1];
            z2 += pv * a.linW[f * 3 + 2];
        }
        float m = fmaxf(z0, fmaxf(z1, z2));
        float l = m + logf(expf(z0 - m) + expf(z1 - m) + expf(z2 - m));
        a.out[b * 3 + 0] = z0 - l;
        a.out[b * 3 + 1] = z1 - l;
        a.out[b * 3 + 2] = z2 - l;
    }
}

// Fast tail: all kept edges intra-graph; finish in LDS (== old K3 fast path).
__device__ void tail_fast(const KArgs& a, int b, int tid, LdsTail& T, int ke, int nk) {
    for (int j = tid; j < nk * FD; j += 256) T.tileA[j] = 0.f;
    __syncthreads();
    for (long long idx = tid; idx < (long long)ke * FD; idx += 256) {
        int e = (int)(idx >> 7), f = (int)(idx & 127);
        int d = a.kedge[2 * e + 1];
        if ((d >> 6) == b) {
            int s = a.kedge[2 * e];            // cross==0 => s in graph b
            float nm = rsqrtf(a.degs[s]) * rsqrtf(a.degs[d]);
            atomicAdd(&T.tileA[(d & 63) * FD + f], nm * T.tileB[(s & 63) * FD + f]);
        }
    }
    __syncthreads();
    // bn2 -> tileA = h2
    for (int j = tid; j < nk * FD; j += 256) {
        int ld = j >> 7, f = j & 127, slot = b * SLOTC + ld;
        float di = rsqrtf(a.degs[slot]);
        float v = T.tileA[j] + di * di * T.tileB[j] + a.b2[f];
        v = fmaxf(v, 0.f);
        v = (v - a.rm2[f]) * rsqrtf(a.rv2[f] + 1e-5f) * a.g2[f] + a.be2[f];
        T.tileA[j] = v;
    }
    __syncthreads();
    // mm3: tileB = tileA @ W3
    for (int j = tid; j < nk * FD; j += 256) {
        int ld = j >> 7, f = j & 127;
        const float* xr = T.tileA + ld * FD;
        float acc = 0.f;
        #pragma unroll 8
        for (int k = 0; k < FD; k++) acc += xr[k] * a.W3[k * FD + f];
        T.tileB[j] = acc;
    }
    __syncthreads();
    for (int j = tid; j < nk * FD; j += 256) T.tileA[j] = 0.f;
    __syncthreads();
    for (long long idx = tid; idx < (long long)ke * FD; idx += 256) {
        int e = (int)(idx >> 7), f = (int)(idx & 127);
        int d = a.kedge[2 * e + 1];
        if ((d >> 6) == b) {
            int s = a.kedge[2 * e];
            float nm = rsqrtf(a.degs[s]) * rsqrtf(a.degs[d]);
            atomicAdd(&T.tileA[(d & 63) * FD + f], nm * T.tileB[(s & 63) * FD + f]);
        }
    }
    __syncthreads();
    // bn3 -> tileA = h3
    for (int j = tid; j < nk * FD; j += 256) {
        int ld = j >> 7, f = j & 127, slot = b * SLOTC + ld;
        float di = rsqrtf(a.degs[slot]);
        float v = T.tileA[j] + di * di * T.tileB[j] + a.b3[f];
        v = fmaxf(v, 0.f);
        v = (v - a.rm3[f]) * rsqrtf(a.rv3[f] + 1e-5f) * a.g3[f] + a.be3[f];
        T.tileA[j] = v;
    }
    __syncthreads();
    tail_out(a, b, tid, T, nk);
}

// Slow tail (cross-graph kept edges exist; reads global hY) == old K4 body.
__device__ void tail_slow(const KArgs& a, int b, int tid, LdsTail& T, int ke, int nk) {
    for (int j = tid; j < nk * FD; j += 256) T.tileA[j] = 0.f;
    __syncthreads();
    for (long long idx = tid; idx < (long long)ke * FD; idx += 256) {
        int e = (int)(idx >> 7), f = (int)(idx & 127);
        int d = a.kedge[2 * e + 1];
        if ((d >> 6) == b) {
            int s = a.kedge[2 * e];
            float nm = rsqrtf(a.degs[s]) * rsqrtf(a.degs[d]);
            atomicAdd(&T.tileA[(d & 63) * FD + f], nm * a.hY[s * FD + f]);
        }
    }
    __syncthreads();
    // bn2 -> tileA = h2_own
    for (int j = tid; j < nk * FD; j += 256) {
        int ld = j >> 7, f = j & 127, slot = b * SLOTC + ld;
        float di = rsqrtf(a.degs[slot]);
        float v = T.tileA[j] + di * di * a.hY[slot * FD + f] + a.b2[f];
        v = fmaxf(v, 0.f);
        v = (v - a.rm2[f]) * rsqrtf(a.rv2[f] + 1e-5f) * a.g2[f] + a.be2[f];
        T.tileA[j] = v;
    }
    __syncthreads();
    // mm3 -> tileB = hYB_own
    for (int j = tid; j < nk * FD; j += 256) {
        int ld = j >> 7, f = j & 127;
        const float* xr = T.tileA + ld * FD;
        float acc = 0.f;
        #pragma unroll 8
        for (int k = 0; k < FD; k++) acc += xr[k] * a.W3[k * FD + f];
        T.tileB[j] = acc;
    }
    __syncthreads();
    for (int j = tid; j < nk * FD; j += 256) T.tileA[j] = 0.f;
    __syncthreads();
    for (long long idx = tid; idx < (long long)ke * FD; idx += 256) {
        int e = (int)(idx >> 7), f = (int)(idx & 127);
        int d = a.kedge[2 * e + 1];
        if ((d >> 6) == b) {
            int s = a.kedge[2 * e];
            if ((s >> 6) == b) {
                float nm = rsqrtf(a.degs[s]) * rsqrtf(a.degs[d]);
                atomicAdd(&T.tileA[(d & 63) * FD + f], nm * T.tileB[(s & 63) * FD + f]);
            }
        }
    }
    __syncthreads();
    // cross sources: recompute hYB[s] on demand (rare fallback)
    for (int e = 0; e < ke; e++) {
        int d = a.kedge[2 * e + 1];
        if ((d >> 6) != b) continue;
        int s = a.kedge[2 * e];
        if ((s >> 6) == b) continue;
        float dis = rsqrtf(a.degs[s]);
        for (int f = tid; f < FD; f += 256) {
            float acc = dis * dis * a.hY[s * FD + f];
            for (int e2 = 0; e2 < ke; e2++) {
                if (a.kedge[2 * e2 + 1] == s) {
                    int u = a.kedge[2 * e2];
                    acc += rsqrtf(a.degs[u]) * dis * a.hY[u * FD + f];
                }
            }
            float v = acc + a.b2[f];
            v = fmaxf(v, 0.f);
            v = (v - a.rm2[f]) * rsqrtf(a.rv2[f] + 1e-5f) * a.g2[f] + a.be2[f];
            T.rowt[f] = v;
        }
        __syncthreads();
        float nm = dis * rsqrtf(a.degs[d]);
        for (int f = tid; f < FD; f += 256) {
            float acc = 0.f;
            #pragma unroll 8
            for (int k = 0; k < FD; k++) acc += T.rowt[k] * a.W3[k * FD + f];
            atomicAdd(&T.tileA[(d & 63) * FD + f], nm * acc);
        }
        __syncthreads();
    }
    // bn3 -> tileA = h3
    for (int j = tid; j < nk * FD; j += 256) {
        int ld = j >> 7, f = j & 127, slot = b * SLOTC + ld;
        float di = rsqrtf(a.degs[slot]);
        float v = T.tileA[j] + di * di * T.tileB[j] + a.b3[f];
        v = fmaxf(v, 0.f);
        v = (v - a.rm3[f]) * rsqrtf(a.rv3[f] + 1e-5f) * a.g3[f] + a.be3[f];
        T.tileA[j] = v;
    }
    __syncthreads();
    tail_out(a, b, tid, T, nk);
}

// ---- Fused cooperative kernel: all 4 phases, 2 grid syncs (3rd only if cross) ----
__global__ __launch_bounds__(256) void k_fused(KArgs a) {
    __shared__ LdsScore L;
    __shared__ LdsTail T;
    cg::grid_group g = cg::this_grid();
    int blk = blockIdx.x, tid = threadIdx.x;

    if (blk < BB) phase_score(a, blk, tid, L);
    g.sync();
    phase_edges(a, blk * 256 + tid, GRID_F * 256);
    g.sync();

    int ke = a.kecnt[0]; if (ke > EMAXE) ke = EMAXE;
    int cross = a.kecnt[1];                  // grid-uniform post-sync
    if (blk < BB) {
        int nk = a.knt[blk];
        tail_common(a, blk, tid, T, ke, nk);
        if (cross == 0) tail_fast(a, blk, tid, T, ke, nk);
        else            tail_write_hY(a, blk, tid, T, nk);
    }
    if (cross != 0) {                        // uniform branch -> uniform sync
        g.sync();
        if (blk < BB) {
            int nk = a.knt[blk];
            tail_slow(a, blk, tid, T, ke, nk);
        }
    }
}

// ---- Fallback standalone kernels (used only if cooperative launch is rejected) ----
__global__ __launch_bounds__(256) void k_scorekeep(KArgs a) {
    __shared__ LdsScore L;
    phase_score(a, blockIdx.x, threadIdx.x, L);
}

__global__ void k_edges(KArgs a) {
    int t = blockIdx.x * 256 + threadIdx.x;
    phase_edges(a, t, 1 << 30);              // single iteration per thread
}

__global__ __launch_bounds__(256) void k_tail_main(KArgs a) {
    __shared__ LdsTail T;
    int b = blockIdx.x, tid = threadIdx.x;
    int ke = a.kecnt[0]; if (ke > EMAXE) ke = EMAXE;
    int cross = a.kecnt[1];
    int nk = a.knt[b];
    tail_common(a, b, tid, T, ke, nk);
    if (cross != 0) { tail_write_hY(a, b, tid, T, nk); return; }
    tail_fast(a, b, tid, T, ke, nk);
}

__global__ __launch_bounds__(256) void k_tail_slow(KArgs a) {
    if (a.kecnt[1] == 0) return;
    __shared__ LdsTail T;
    int b = blockIdx.x, tid = threadIdx.x;
    int ke = a.kecnt[0]; if (ke > EMAXE) ke = EMAXE;
    int nk = a.knt[b];
    tail_slow(a, b, tid, T, ke, nk);
}

extern "C" void kernel_launch(void* const* d_in, const int* in_sizes, int n_in,
                              void* d_out, int out_size, void* d_ws, size_t ws_size,
                              hipStream_t stream) {
    (void)in_sizes; (void)n_in; (void)out_size; (void)ws_size;
    const float* x    = (const float*)d_in[0];
    const int*   ei   = (const int*)d_in[1];
    const int*   bidx = (const int*)d_in[2];
    const float* tw   = (const float*)d_in[3];

    char* w = (char*)d_ws;
    auto take = [&](size_t bytes) { char* r = w; w += (bytes + 255) & ~(size_t)255; return r; };
    int*      kecnt  = (int*)take(16);
    int*      knt    = (int*)take((size_t)BB * 4);
    unsigned* kfbits = (unsigned*)take((size_t)NWORDS * 4);
    int*      nslot  = (int*)take((size_t)NN * 4);
    float*    degs   = (float*)take((size_t)KSLOTS * 4);
    float2*   h0s    = (float2*)take((size_t)KSLOTS * 8);
    int*      kedge  = (int*)take((size_t)EMAXE * 8);
    float*    hY     = (float*)take((size_t)KSLOTS * FD * 4);

    KArgs ka;
    ka.x = (const float2*)x; ka.src4 = (const int4*)ei; ka.ei = ei; ka.bidx = bidx; ka.tw = tw;
    ka.W1 = (const float*)d_in[4];  ka.b1 = (const float*)d_in[5];  ka.g1 = (const float*)d_in[6];
    ka.be1= (const float*)d_in[7];  ka.rm1= (const float*)d_in[8];  ka.rv1= (const float*)d_in[9];
    ka.W2 = (const float*)d_in[10]; ka.b2 = (const float*)d_in[11]; ka.g2 = (const float*)d_in[12];
    ka.be2= (const float*)d_in[13]; ka.rm2= (const float*)d_in[14]; ka.rv2= (const float*)d_in[15];
    ka.W3 = (const float*)d_in[16]; ka.b3 = (const float*)d_in[17]; ka.g3 = (const float*)d_in[18];
    ka.be3= (const float*)d_in[19]; ka.rm3= (const float*)d_in[20]; ka.rv3= (const float*)d_in[21];
    ka.linW = (const float*)d_in[22]; ka.linb = (const float*)d_in[23];
    ka.kfbits = kfbits; ka.nslot = nslot; ka.knt = knt; ka.degs = degs; ka.h0s = h0s;
    ka.kedge = kedge; ka.kecnt = kecnt; ka.hY = hY; ka.out = (float*)d_out;

    void* params[] = { (void*)&ka };
    hipError_t err = hipLaunchCooperativeKernel(reinterpret_cast<const void*>(k_fused),
                                                dim3(GRID_F), dim3(256), params, 0, stream);
    if (err != hipSuccess) {
        // fallback: original 4-kernel chain (identical math)
        hipLaunchKernelGGL(k_scorekeep, dim3(BB), dim3(256), 0, stream, ka);
        hipLaunchKernelGGL(k_edges, dim3((EE / 4 + 255) / 256), dim3(256), 0, stream, ka);
        hipLaunchKernelGGL(k_tail_main, dim3(BB), dim3(256), 0, stream, ka);
        hipLaunchKernelGGL(k_tail_slow, dim3(BB), dim3(256), 0, stream, ka);
    }
}